// Round 6
// baseline (1033.573 us; speedup 1.0000x reference)
//
#include <hip/hip_runtime.h>
#include <hip/hip_bf16.h>
#include <math.h>

#define NCLS 19
#define MCOMP 5
#define AFEAT 64
#define IGNORE_L 255
#define LOG2PI 1.8378770664093453f

// 20 classes x 8 component-slots = 160 rows (slots 5..7 and class 19 are pads)
#define ROWS 160
// ws byte offsets
#define WAM_B 0                      // bf16 [160][128] : 40960 B  ([nl | iv])
#define WAL_B 40960                  // bf16 [160][64]  : 20480 B  (loc)
#define CST_B 61440                  // f32  [160]      : 640 B    (pads = 1e30)
#define MT_B  62080                  // bf16 [20][64]   : 2560 B   (row 19 = 0)
#define DR_B  64640                  // f32  [20]       : 80 B     (DR[19] = 0)
#define ACC_B 64768                  // f32  [2]        : sum, cnt
#define VAL_B 64832                  // u64  [4096]     : validity bitmask

typedef __attribute__((ext_vector_type(8))) short bf16x8;
typedef __attribute__((ext_vector_type(4))) float f32x4;

__device__ inline float b2f(short s) {
    return __uint_as_float(((unsigned int)(unsigned short)s) << 16);
}
__device__ inline short f2b(float f) {
    __hip_bfloat16 h = __float2bfloat16(f);
    return *reinterpret_cast<short*>(&h);
}

// ---------------- precompute: permuted bf16 weights + constants ----------------
__global__ void precompute_kernel(const float* __restrict__ mean,
                                  const float* __restrict__ cov,
                                  const float* __restrict__ tmem,
                                  const float* __restrict__ ct,
                                  const float* __restrict__ cs,
                                  char* __restrict__ wsb) {
    int blk = blockIdx.x;
    int a = threadIdx.x;  // 64 threads
    short* wam = (short*)(wsb + WAM_B);
    short* wal = (short*)(wsb + WAL_B);
    float* cst = (float*)(wsb + CST_B);
    short* mtb = (short*)(wsb + MT_B);
    float* dr  = (float*)(wsb + DR_B);
    float* acc = (float*)(wsb + ACC_B);

    if (blk < ROWS) {
        int r = blk, c = r >> 3, m = r & 7;
        if (c < NCLS && m < MCOMP) {
            int k = c * MCOMP + m;
            float lo = mean[k * AFEAT + a];
            float cv = cov[k * AFEAT + a];
            float iv = 1.0f / (cv * cv);
            wam[r * 128 + a]      = f2b(-2.0f * lo * iv);  // k-half 0: pairs with f
            wam[r * 128 + 64 + a] = f2b(iv);               // k-half 1: pairs with q=f^2
            wal[r * 64 + a]       = f2b(lo);
            float s1 = lo * lo * iv;
            float s2 = logf(cv);
            for (int off = 32; off > 0; off >>= 1) {
                s1 += __shfl_xor(s1, off, 64);
                s2 += __shfl_xor(s2, off, 64);
            }
            if (a == 0) cst[r] = AFEAT * LOG2PI + 2.0f * s2 + s1;
        } else {
            wam[r * 128 + a] = 0; wam[r * 128 + 64 + a] = 0;
            wal[r * 64 + a] = 0;
            if (a == 0) cst[r] = 1e30f;   // pad: exp(-0.5*cst - G) -> 0
        }
    } else if (blk < ROWS + 20) {
        int c = blk - ROWS;
        if (c < NCLS) {
            const float* p = tmem + ((size_t)c * AFEAT + a) * 100;
            float s = 0.f;
            for (int j = 0; j < 100; ++j) s += p[j];
            s *= 0.01f;
            float n2 = s * s;
            for (int off = 32; off > 0; off >>= 1) n2 += __shfl_xor(n2, off, 64);
            float den = fmaxf(sqrtf(n2), 1e-12f);
            mtb[c * AFEAT + a] = f2b(s / den);
        } else {
            mtb[c * AFEAT + a] = 0;
        }
    } else {
        if (a < 20) {
            float r = 0.f;
            if (a < NCLS) {
                r = ct[a] / cs[a];
                if (isnan(r)) r = 0.f;
                else if (isinf(r)) r = (r > 0.f) ? 3.402823466e38f : -3.402823466e38f;
            }
            dr[a] = r;
        }
        if (a == 32) { acc[0] = 0.f; acc[1] = 0.f; }
    }
}

// ---------------- validity bitmask (majority >= 12/16 of a real class) ----------
__global__ void valid_kernel(const int* __restrict__ mask,
                             unsigned long long* __restrict__ vwords) {
    int n = blockIdx.x * 256 + threadIdx.x;
    int b = n >> 16, rem = n & 65535, y = rem >> 8, x = rem & 255;
    const int* mp = mask + (((size_t)b << 10) + ((size_t)y << 2)) * 1024 + ((size_t)x << 2);
    int v[16];
#pragma unroll
    for (int r = 0; r < 4; ++r) {
        int4 q = *reinterpret_cast<const int4*>(mp + (size_t)r * 1024);
        v[r * 4 + 0] = q.x; v[r * 4 + 1] = q.y; v[r * 4 + 2] = q.z; v[r * 4 + 3] = q.w;
    }
    bool valid = false;
#pragma unroll
    for (int i = 0; i < 16; ++i) {
        int cnt = 0;
#pragma unroll
        for (int j = 0; j < 16; ++j) cnt += (v[j] == v[i]) ? 1 : 0;
        if (v[i] != IGNORE_L && cnt >= 12) valid = true;
    }
    unsigned long long bm = __ballot(valid);
    if ((threadIdx.x & 63) == 0) vwords[n >> 6] = bm;
}

// ---------------- main MFMA kernel ----------------
// 512 threads = 8 waves; each wave does 4 tiles of 16 pixels.
__global__ __launch_bounds__(512, 4)
void protogmm_kernel(const float* __restrict__ feat,
                     const char* __restrict__ wsb,
                     const unsigned long long* __restrict__ vwords,
                     float* __restrict__ accg) {
    __shared__ short wamL[ROWS * 128];   // 40960 B, slot-swizzled
    __shared__ short walL[ROWS * 64];    // 20480 B, slot-swizzled
    __shared__ float cstL[ROWS];         // 640 B
    __shared__ short mtL[20 * 64];       // 2560 B
    __shared__ float drL[20];            // 80 B

    int tid = threadIdx.x;
    // ---- stage weights to LDS (swizzle 16B slots by row&7 to kill bank conflicts)
    {
        const uint4* s0 = (const uint4*)(wsb + WAM_B);
        for (int i = tid; i < 2560; i += 512) {
            int row = i >> 4, slot = i & 15;
            *(uint4*)((char*)wamL + row * 256 + ((slot ^ (row & 7)) << 4)) = s0[i];
        }
        const uint4* s1 = (const uint4*)(wsb + WAL_B);
        for (int i = tid; i < 1280; i += 512) {
            int row = i >> 3, slot = i & 7;
            *(uint4*)((char*)walL + row * 128 + ((slot ^ (row & 7)) << 4)) = s1[i];
        }
        const float* s2 = (const float*)(wsb + CST_B);
        for (int i = tid; i < ROWS; i += 512) cstL[i] = s2[i];
        const uint4* s3 = (const uint4*)(wsb + MT_B);
        for (int i = tid; i < 160; i += 512) ((uint4*)mtL)[i] = s3[i];
        const float* s4 = (const float*)(wsb + DR_B);
        if (tid < 20) drL[tid] = s4[tid];
    }
    __syncthreads();

    int lane = tid & 63, l15 = lane & 15, g = lane >> 4, rx = l15 & 7;
    int wv = blockIdx.x * 8 + (tid >> 6);
    int p = g >> 1;  // class parity handled by this lane

    float cesum = 0.f, cntsum = 0.f;

#pragma unroll 1
    for (int it = 0; it < 4; ++it) {
        int tile = wv * 4 + it;
        int n0 = tile << 4;
        int b = n0 >> 16, y = (n0 >> 8) & 255, x0 = n0 & 255;

        // ---- load this lane's feature chunks: a in [8g,8g+8) and [32+8g,32+8g+8)
        const float* fb = feat + (size_t)b * (AFEAT * 65536) + y * 256 + x0 + l15;
        float fvv[16];
        float n2 = 0.f;
#pragma unroll
        for (int j = 0; j < 8; ++j) {
            fvv[j]     = fb[(size_t)(8 * g + j) * 65536];
            fvv[8 + j] = fb[(size_t)(32 + 8 * g + j) * 65536];
        }
#pragma unroll
        for (int j = 0; j < 16; ++j) n2 = fmaf(fvv[j], fvv[j], n2);
        n2 += __shfl_xor(n2, 16, 64);
        n2 += __shfl_xor(n2, 32, 64);
        float inv = 1.0f / fmaxf(sqrtf(n2), 1e-12f);
#pragma unroll
        for (int j = 0; j < 16; ++j) fvv[j] *= inv;

        // ---- sim: sd[t] = f . mean_target[2t+p]  (VALU, both parities then select)
        float sd[10];
#pragma unroll
        for (int t = 0; t < 10; ++t) {
            bf16x8 m0a = *(const bf16x8*)(mtL + (2 * t) * 64 + 8 * g);
            bf16x8 m0b = *(const bf16x8*)(mtL + (2 * t) * 64 + 32 + 8 * g);
            bf16x8 m1a = *(const bf16x8*)(mtL + (2 * t + 1) * 64 + 8 * g);
            bf16x8 m1b = *(const bf16x8*)(mtL + (2 * t + 1) * 64 + 32 + 8 * g);
            float p0 = 0.f, p1 = 0.f;
#pragma unroll
            for (int j = 0; j < 8; ++j) {
                p0 = fmaf(fvv[j], b2f(m0a[j]), p0);
                p0 = fmaf(fvv[8 + j], b2f(m0b[j]), p0);
                p1 = fmaf(fvv[j], b2f(m1a[j]), p1);
                p1 = fmaf(fvv[8 + j], b2f(m1b[j]), p1);
            }
            p0 += __shfl_xor(p0, 16, 64); p0 += __shfl_xor(p0, 32, 64);
            p1 += __shfl_xor(p1, 16, 64); p1 += __shfl_xor(p1, 32, 64);
            sd[t] = p ? p1 : p0;
        }

        // ---- pack bf16 fragments: kt0,1 = f (a 0..63), kt2,3 = f^2
        bf16x8 F[4];
#pragma unroll
        for (int j = 0; j < 8; ++j) {
            F[0][j] = f2b(fvv[j]);
            F[1][j] = f2b(fvv[8 + j]);
            F[2][j] = f2b(fvv[j] * fvv[j]);
            F[3][j] = f2b(fvv[8 + j] * fvv[8 + j]);
        }

        // ---- maha GEMM: acc = cst + [nl|iv] . [f|q]
        f32x4 acc[10];
#pragma unroll
        for (int t = 0; t < 10; ++t) {
            acc[t] = *(const f32x4*)(cstL + 16 * t + 4 * g);
#pragma unroll
            for (int kt = 0; kt < 4; ++kt) {
                bf16x8 wa = *(const bf16x8*)((char*)wamL + (16 * t + l15) * 256 +
                                             (((4 * kt + g) ^ rx) << 4));
                acc[t] = __builtin_amdgcn_mfma_f32_16x16x32_bf16(wa, F[kt], acc[t], 0, 0, 0);
            }
        }

        // ---- global max of lp = -0.5*acc  (pads have acc ~ 1e30, never the min)
        float mn = 1e30f;
#pragma unroll
        for (int t = 0; t < 10; ++t) {
            mn = fminf(mn, fminf(fminf(acc[t][0], acc[t][1]), fminf(acc[t][2], acc[t][3])));
        }
        mn = fminf(mn, __shfl_xor(mn, 16, 64));
        mn = fminf(mn, __shfl_xor(mn, 32, 64));
        float G = -0.5f * mn;

        // ---- S_c = sum_m exp(lp - G): in-lane 4 + partner half via xor16
        float Sc[10];
#pragma unroll
        for (int t = 0; t < 10; ++t) {
            float e0 = __expf(fmaf(acc[t][0], -0.5f, -G));
            float e1 = __expf(fmaf(acc[t][1], -0.5f, -G));
            float e2 = __expf(fmaf(acc[t][2], -0.5f, -G));
            float e3 = __expf(fmaf(acc[t][3], -0.5f, -G));
            float st = (e0 + e1) + (e2 + e3);
            Sc[t] = st + __shfl_xor(st, 16, 64);
        }

        // ---- logits GEMM + per-class max (mask pad m-slots)
        float lmx[10];
#pragma unroll
        for (int t = 0; t < 10; ++t) {
            f32x4 a2 = {0.f, 0.f, 0.f, 0.f};
#pragma unroll
            for (int kt = 0; kt < 2; ++kt) {
                bf16x8 wl = *(const bf16x8*)((char*)walL + (16 * t + l15) * 128 +
                                             (((4 * kt + g) ^ rx) << 4));
                a2 = __builtin_amdgcn_mfma_f32_16x16x32_bf16(wl, F[kt], a2, 0, 0, 0);
            }
            float d0 = a2[0] * 0.01f, d1 = a2[1] * 0.01f;
            float d2 = a2[2] * 0.01f, d3 = a2[3] * 0.01f;
            if (g & 1) { d1 = -1e30f; d2 = -1e30f; d3 = -1e30f; }  // m-slots 5..7 pad
            float lt = fmaxf(fmaxf(d0, d1), fmaxf(d2, d3));
            if (t == 9 && (g & 2)) lt = -1e30f;                    // class 19 pad
            lmx[t] = fmaxf(lt, __shfl_xor(lt, 16, 64));
        }

        // ---- value (denominators cancel), argmax, LSE over classes
        float bestv = -1.f, bestc = 0.f, bestl = 0.f, ls = 0.f;
#pragma unroll
        for (int t = 0; t < 10; ++t) {
            float dr = drL[2 * t + p];
            float val = dr * __expf(sd[t]) * Sc[t];
            ls += __expf(lmx[t]);
            float cls = (float)(2 * t + p);
            bool better = val > bestv;
            bestc = better ? cls : bestc;
            bestl = better ? lmx[t] : bestl;
            bestv = better ? val : bestv;
        }
        {   // merge other parity (xor32); xor16 partner is identical by construction
            float ov = __shfl_xor(bestv, 32, 64);
            float oc = __shfl_xor(bestc, 32, 64);
            float ol = __shfl_xor(bestl, 32, 64);
            bool take = (ov > bestv) || (ov == bestv && oc < bestc);
            bestv = take ? ov : bestv;
            bestl = take ? ol : bestl;
            bestc = take ? oc : bestc;
            ls += __shfl_xor(ls, 32, 64);
        }
        float ce = __logf(ls) - bestl;

        // ---- validity + accumulate (count each pixel once: g==0 lanes)
        unsigned long long w = vwords[tile >> 2];
        float vb = (float)((w >> ((n0 & 63) + l15)) & 1ull);
        float own = (g == 0) ? 1.f : 0.f;
        cesum  = fmaf(own * vb, ce, cesum);
        cntsum += own * vb;
    }

    // ---- wave reduce + atomic
#pragma unroll
    for (int off = 32; off > 0; off >>= 1) {
        cesum  += __shfl_xor(cesum, off, 64);
        cntsum += __shfl_xor(cntsum, off, 64);
    }
    if (lane == 0) {
        atomicAdd(&accg[0], cesum);
        atomicAdd(&accg[1], cntsum);
    }
}

__global__ void finalize_kernel(const float* __restrict__ acc, float* __restrict__ out) {
    out[0] = acc[0] / fmaxf(acc[1], 1.0f);
}

extern "C" void kernel_launch(void* const* d_in, const int* in_sizes, int n_in,
                              void* d_out, int out_size, void* d_ws, size_t ws_size,
                              hipStream_t stream) {
    const float* feat = (const float*)d_in[0];
    const int*   mask = (const int*)d_in[1];
    const float* mean = (const float*)d_in[2];
    const float* cov  = (const float*)d_in[3];
    const float* tmem = (const float*)d_in[4];
    const float* ct   = (const float*)d_in[5];
    const float* cs   = (const float*)d_in[6];
    float* out = (float*)d_out;
    char*  wsb = (char*)d_ws;

    precompute_kernel<<<ROWS + 20 + 1, 64, 0, stream>>>(mean, cov, tmem, ct, cs, wsb);
    valid_kernel<<<1024, 256, 0, stream>>>(mask, (unsigned long long*)(wsb + VAL_B));
    protogmm_kernel<<<512, 512, 0, stream>>>(feat, wsb,
                                             (const unsigned long long*)(wsb + VAL_B),
                                             (float*)(wsb + ACC_B));
    finalize_kernel<<<1, 1, 0, stream>>>((const float*)(wsb + ACC_B), out);
}

// Round 7
// 248.940 us; speedup vs baseline: 4.1519x; 4.1519x over previous
//
#include <hip/hip_runtime.h>
#include <hip/hip_bf16.h>
#include <math.h>

#define NCLS 19
#define MCOMP 5
#define AFEAT 64
#define IGNORE_L 255
#define LOG2PI 1.8378770664093453f

// 20 classes x 8 component-slots = 160 rows (slots 5..7 and class 19 are pads)
#define ROWS 160
// ws byte offsets
#define WAM_B 0                      // bf16 [160][128] : 40960 B  ([nl | iv])
#define WAL_B 40960                  // bf16 [160][64]  : 20480 B  (loc)
#define CST_B 61440                  // f32  [160]      : 640 B    (pads = 1e30)
#define MT_B  62080                  // bf16 [20][64]   : 2560 B   (row 19 = 0)
#define DR_B  64640                  // f32  [20]       : 80 B     (DR[19] = 0)
#define ACC_B 64768                  // f32  [2]        : sum, cnt
#define VAL_B 64832                  // u64  [4096]     : validity bitmask

typedef __attribute__((ext_vector_type(8))) short bf16x8;
typedef __attribute__((ext_vector_type(4))) float f32x4;

__device__ inline float b2f(short s) {
    return __uint_as_float(((unsigned int)(unsigned short)s) << 16);
}
__device__ inline short f2b(float f) {
    __hip_bfloat16 h = __float2bfloat16(f);
    return *reinterpret_cast<short*>(&h);
}

// ---------------- precompute: permuted bf16 weights + constants ----------------
__global__ void precompute_kernel(const float* __restrict__ mean,
                                  const float* __restrict__ cov,
                                  const float* __restrict__ tmem,
                                  const float* __restrict__ ct,
                                  const float* __restrict__ cs,
                                  char* __restrict__ wsb) {
    int blk = blockIdx.x;
    int a = threadIdx.x;  // 64 threads
    short* wam = (short*)(wsb + WAM_B);
    short* wal = (short*)(wsb + WAL_B);
    float* cst = (float*)(wsb + CST_B);
    short* mtb = (short*)(wsb + MT_B);
    float* dr  = (float*)(wsb + DR_B);
    float* acc = (float*)(wsb + ACC_B);

    if (blk < ROWS) {
        int r = blk, c = r >> 3, m = r & 7;
        if (c < NCLS && m < MCOMP) {
            int k = c * MCOMP + m;
            float lo = mean[k * AFEAT + a];
            float cv = cov[k * AFEAT + a];
            float iv = 1.0f / (cv * cv);
            wam[r * 128 + a]      = f2b(-2.0f * lo * iv);  // k-half 0: pairs with f
            wam[r * 128 + 64 + a] = f2b(iv);               // k-half 1: pairs with q=f^2
            wal[r * 64 + a]       = f2b(lo);
            float s1 = lo * lo * iv;
            float s2 = logf(cv);
            for (int off = 32; off > 0; off >>= 1) {
                s1 += __shfl_xor(s1, off, 64);
                s2 += __shfl_xor(s2, off, 64);
            }
            if (a == 0) cst[r] = AFEAT * LOG2PI + 2.0f * s2 + s1;
        } else {
            wam[r * 128 + a] = 0; wam[r * 128 + 64 + a] = 0;
            wal[r * 64 + a] = 0;
            if (a == 0) cst[r] = 1e30f;   // pad: exp(-0.5*cst - G) -> 0
        }
    } else if (blk < ROWS + 20) {
        int c = blk - ROWS;
        if (c < NCLS) {
            const float* p = tmem + ((size_t)c * AFEAT + a) * 100;
            float s = 0.f;
            for (int j = 0; j < 100; ++j) s += p[j];
            s *= 0.01f;
            float n2 = s * s;
            for (int off = 32; off > 0; off >>= 1) n2 += __shfl_xor(n2, off, 64);
            float den = fmaxf(sqrtf(n2), 1e-12f);
            mtb[c * AFEAT + a] = f2b(s / den);
        } else {
            mtb[c * AFEAT + a] = 0;
        }
    } else {
        if (a < 20) {
            float r = 0.f;
            if (a < NCLS) {
                r = ct[a] / cs[a];
                if (isnan(r)) r = 0.f;
                else if (isinf(r)) r = (r > 0.f) ? 3.402823466e38f : -3.402823466e38f;
            }
            dr[a] = r;
        }
        if (a == 32) { acc[0] = 0.f; acc[1] = 0.f; }
    }
}

// ---------------- validity bitmask (majority >= 12/16 of a real class) ----------
__global__ void valid_kernel(const int* __restrict__ mask,
                             unsigned long long* __restrict__ vwords) {
    int n = blockIdx.x * 256 + threadIdx.x;
    int b = n >> 16, rem = n & 65535, y = rem >> 8, x = rem & 255;
    const int* mp = mask + (((size_t)b << 10) + ((size_t)y << 2)) * 1024 + ((size_t)x << 2);
    int v[16];
#pragma unroll
    for (int r = 0; r < 4; ++r) {
        int4 q = *reinterpret_cast<const int4*>(mp + (size_t)r * 1024);
        v[r * 4 + 0] = q.x; v[r * 4 + 1] = q.y; v[r * 4 + 2] = q.z; v[r * 4 + 3] = q.w;
    }
    bool valid = false;
#pragma unroll
    for (int i = 0; i < 16; ++i) {
        int cnt = 0;
#pragma unroll
        for (int j = 0; j < 16; ++j) cnt += (v[j] == v[i]) ? 1 : 0;
        if (v[i] != IGNORE_L && cnt >= 12) valid = true;
    }
    unsigned long long bm = __ballot(valid);
    if ((threadIdx.x & 63) == 0) vwords[n >> 6] = bm;
}

// ---------------- main MFMA kernel (online class-tile loop, low VGPR) ----------
// 512 threads = 8 waves; each wave does 4 tiles of 16 pixels.
__global__ __launch_bounds__(512, 2)
void protogmm_kernel(const float* __restrict__ feat,
                     const char* __restrict__ wsb,
                     const unsigned long long* __restrict__ vwords,
                     float* __restrict__ accg) {
    __shared__ short wamL[ROWS * 128];   // 40960 B, slot-swizzled
    __shared__ short walL[ROWS * 64];    // 20480 B, slot-swizzled
    __shared__ float cstL[ROWS];         // 640 B
    __shared__ short mtL[20 * 64];       // 2560 B
    __shared__ float drL[20];            // 80 B

    int tid = threadIdx.x;
    // ---- stage weights to LDS (swizzle 16B slots by row&7 to kill bank conflicts)
    {
        const uint4* s0 = (const uint4*)(wsb + WAM_B);
        for (int i = tid; i < 2560; i += 512) {
            int row = i >> 4, slot = i & 15;
            *(uint4*)((char*)wamL + row * 256 + ((slot ^ (row & 7)) << 4)) = s0[i];
        }
        const uint4* s1 = (const uint4*)(wsb + WAL_B);
        for (int i = tid; i < 1280; i += 512) {
            int row = i >> 3, slot = i & 7;
            *(uint4*)((char*)walL + row * 128 + ((slot ^ (row & 7)) << 4)) = s1[i];
        }
        const float* s2 = (const float*)(wsb + CST_B);
        for (int i = tid; i < ROWS; i += 512) cstL[i] = s2[i];
        const uint4* s3 = (const uint4*)(wsb + MT_B);
        for (int i = tid; i < 160; i += 512) ((uint4*)mtL)[i] = s3[i];
        const float* s4 = (const float*)(wsb + DR_B);
        if (tid < 20) drL[tid] = s4[tid];
    }
    __syncthreads();

    int lane = tid & 63, l15 = lane & 15, g = lane >> 4, rx = l15 & 7;
    int wv = blockIdx.x * 8 + (tid >> 6);
    int p = g >> 1;  // class parity handled by this lane

    float cesum = 0.f, cntsum = 0.f;

#pragma unroll 1
    for (int it = 0; it < 4; ++it) {
        int tile = wv * 4 + it;
        int n0 = tile << 4;
        int b = n0 >> 16, y = (n0 >> 8) & 255, x0 = n0 & 255;

        // ---- load feature chunks (a in [8g,8g+8) and [32+8g,+8)), norm, pack bf16
        bf16x8 F[4];
        {
            const float* fb = feat + (size_t)b * (AFEAT * 65536) + y * 256 + x0 + l15;
            float fa[8], fc[8];
            float n2 = 0.f;
#pragma unroll
            for (int j = 0; j < 8; ++j) {
                fa[j] = fb[(size_t)(8 * g + j) * 65536];
                fc[j] = fb[(size_t)(32 + 8 * g + j) * 65536];
            }
#pragma unroll
            for (int j = 0; j < 8; ++j) {
                n2 = fmaf(fa[j], fa[j], n2);
                n2 = fmaf(fc[j], fc[j], n2);
            }
            n2 += __shfl_xor(n2, 16, 64);
            n2 += __shfl_xor(n2, 32, 64);
            float inv = 1.0f / fmaxf(sqrtf(n2), 1e-12f);
#pragma unroll
            for (int j = 0; j < 8; ++j) {
                float u = fa[j] * inv, w2 = fc[j] * inv;
                F[0][j] = f2b(u);
                F[1][j] = f2b(w2);
                F[2][j] = f2b(u * u);
                F[3][j] = f2b(w2 * w2);
            }
        }

        // online state (per lane; scale grun shared by the 4 lanes of each pixel)
        float grun = -1e30f;
        float bestv = -1.0f, bestc = 0.f, bestl = 0.f, ls = 0.f;

#pragma unroll 1
        for (int t = 0; t < 10; ++t) {
            // ---- maha GEMM: acc = cst + [nl|iv] . [f|q]
            f32x4 acc = *(const f32x4*)(cstL + 16 * t + 4 * g);
#pragma unroll
            for (int kt = 0; kt < 4; ++kt) {
                bf16x8 wa = *(const bf16x8*)((char*)wamL + (16 * t + l15) * 256 +
                                             (((4 * kt + g) ^ rx) << 4));
                acc = __builtin_amdgcn_mfma_f32_16x16x32_bf16(wa, F[kt], acc, 0, 0, 0);
            }

            // ---- logits GEMM + per-class max (mask pad m-slots)
            f32x4 a2 = {0.f, 0.f, 0.f, 0.f};
#pragma unroll
            for (int kt = 0; kt < 2; ++kt) {
                bf16x8 wl = *(const bf16x8*)((char*)walL + (16 * t + l15) * 128 +
                                             (((4 * kt + g) ^ rx) << 4));
                a2 = __builtin_amdgcn_mfma_f32_16x16x32_bf16(wl, F[kt], a2, 0, 0, 0);
            }
            float d0 = a2[0] * 0.01f, d1 = a2[1] * 0.01f;
            float d2 = a2[2] * 0.01f, d3 = a2[3] * 0.01f;
            if (g & 1) { d1 = -1e30f; d2 = -1e30f; d3 = -1e30f; }  // m-slots 5..7 pad
            float lt = fmaxf(fmaxf(d0, d1), fmaxf(d2, d3));
            if (t == 9 && (g & 2)) lt = -1e30f;                    // class 19 pad
            float lmx = fmaxf(lt, __shfl_xor(lt, 16, 64));
            ls += __expf(lmx);

            // ---- running max of lp = -0.5*acc (pads acc~1e30 excluded by min)
            float mn = fminf(fminf(acc[0], acc[1]), fminf(acc[2], acc[3]));
            mn = fminf(mn, __shfl_xor(mn, 16, 64));
            mn = fminf(mn, __shfl_xor(mn, 32, 64));
            float gnew = fmaxf(grun, -0.5f * mn);
            float sold = __expf(grun - gnew);   // first iter: exp(-1e30)=0

            // ---- S_c = sum_m exp(lp - gnew): in-lane 4 + partner half via xor16
            float e0 = __expf(fmaf(acc[0], -0.5f, -gnew));
            float e1 = __expf(fmaf(acc[1], -0.5f, -gnew));
            float e2 = __expf(fmaf(acc[2], -0.5f, -gnew));
            float e3 = __expf(fmaf(acc[3], -0.5f, -gnew));
            float st = (e0 + e1) + (e2 + e3);
            float Sc = st + __shfl_xor(st, 16, 64);

            // ---- sim dots for both classes of this tile (from bf16 fragments)
            const short* m0a = mtL + (2 * t) * 64 + 8 * g;
            const short* m1a = mtL + (2 * t + 1) * 64 + 8 * g;
            float p0 = 0.f, p1 = 0.f;
#pragma unroll
            for (int j = 0; j < 8; ++j) {
                float u = b2f(F[0][j]), w2 = b2f(F[1][j]);
                p0 = fmaf(u, b2f(m0a[j]), p0);
                p0 = fmaf(w2, b2f(m0a[32 + j]), p0);
                p1 = fmaf(u, b2f(m1a[j]), p1);
                p1 = fmaf(w2, b2f(m1a[32 + j]), p1);
            }
            p0 += __shfl_xor(p0, 16, 64); p0 += __shfl_xor(p0, 32, 64);
            p1 += __shfl_xor(p1, 16, 64); p1 += __shfl_xor(p1, 32, 64);
            float sd = p ? p1 : p0;

            // ---- value argmax with running rescale (softmax denominators cancel)
            float val = drL[2 * t + p] * __expf(sd) * Sc;
            bestv *= sold;
            if (val > bestv) { bestv = val; bestc = (float)(2 * t + p); bestl = lmx; }
            grun = gnew;
        }

        // ---- merge other parity (xor32); xor16 partner identical by construction
        {
            float ov = __shfl_xor(bestv, 32, 64);
            float oc = __shfl_xor(bestc, 32, 64);
            float ol = __shfl_xor(bestl, 32, 64);
            bool take = (ov > bestv) || (ov == bestv && oc < bestc);
            bestv = take ? ov : bestv;
            bestl = take ? ol : bestl;
            bestc = take ? oc : bestc;
            ls += __shfl_xor(ls, 32, 64);
        }
        float ce = __logf(ls) - bestl;

        // ---- validity + accumulate (count each pixel once: g==0 lanes)
        unsigned long long w = vwords[tile >> 2];
        float vb = (float)((w >> ((n0 & 63) + l15)) & 1ull);
        float own = (g == 0) ? 1.f : 0.f;
        cesum  = fmaf(own * vb, ce, cesum);
        cntsum += own * vb;
    }

    // ---- wave reduce + atomic
#pragma unroll
    for (int off = 32; off > 0; off >>= 1) {
        cesum  += __shfl_xor(cesum, off, 64);
        cntsum += __shfl_xor(cntsum, off, 64);
    }
    if (lane == 0) {
        atomicAdd(&accg[0], cesum);
        atomicAdd(&accg[1], cntsum);
    }
}

__global__ void finalize_kernel(const float* __restrict__ acc, float* __restrict__ out) {
    out[0] = acc[0] / fmaxf(acc[1], 1.0f);
}

extern "C" void kernel_launch(void* const* d_in, const int* in_sizes, int n_in,
                              void* d_out, int out_size, void* d_ws, size_t ws_size,
                              hipStream_t stream) {
    const float* feat = (const float*)d_in[0];
    const int*   mask = (const int*)d_in[1];
    const float* mean = (const float*)d_in[2];
    const float* cov  = (const float*)d_in[3];
    const float* tmem = (const float*)d_in[4];
    const float* ct   = (const float*)d_in[5];
    const float* cs   = (const float*)d_in[6];
    float* out = (float*)d_out;
    char*  wsb = (char*)d_ws;

    precompute_kernel<<<ROWS + 20 + 1, 64, 0, stream>>>(mean, cov, tmem, ct, cs, wsb);
    valid_kernel<<<1024, 256, 0, stream>>>(mask, (unsigned long long*)(wsb + VAL_B));
    protogmm_kernel<<<512, 512, 0, stream>>>(feat, wsb,
                                             (const unsigned long long*)(wsb + VAL_B),
                                             (float*)(wsb + ACC_B));
    finalize_kernel<<<1, 1, 0, stream>>>((const float*)(wsb + ACC_B), out);
}